// Round 1
// baseline (331.447 us; speedup 1.0000x reference)
//
#include <hip/hip_runtime.h>
#include <cstdint>

#define NB    8
#define NSEQ  4096
#define CDIM  256
#define NTOK  (NB*NSEQ)

typedef _Float16 half8  __attribute__((ext_vector_type(8)));
typedef _Float16 half4v __attribute__((ext_vector_type(4)));
typedef float    f32x4  __attribute__((ext_vector_type(4)));

typedef unsigned int u32_g __attribute__((address_space(1)));
typedef unsigned int u32_l __attribute__((address_space(3)));

// direct global->LDS, 16B per lane; LDS dest is wave-uniform base + lane*16
__device__ __forceinline__ void gload_lds16(const void* g, void* l) {
  __builtin_amdgcn_global_load_lds((u32_g*)(uintptr_t)g,
                                   (u32_l*)(uint32_t)(uintptr_t)l, 16, 0, 0);
}

__device__ __forceinline__ f32x4 vmax4(f32x4 a, f32x4 b) {
  f32x4 r;
  r[0] = fmaxf(a[0], b[0]); r[1] = fmaxf(a[1], b[1]);
  r[2] = fmaxf(a[2], b[2]); r[3] = fmaxf(a[3], b[3]);
  return r;
}

// ---------------- LayerNorm: one wave per token (C=256 = 64 lanes x float4)
__global__ __launch_bounds__(256) void ln_kernel(
    const float* __restrict__ x, const float* __restrict__ gam,
    const float* __restrict__ bet, float* __restrict__ xnf,
    _Float16* __restrict__ xnh) {
  const int lane = threadIdx.x & 63;
  const size_t tok = (size_t)blockIdx.x * 4 + (threadIdx.x >> 6);
  const float4 v = ((const float4*)(x + tok * CDIM))[lane];
  float s  = v.x + v.y + v.z + v.w;
  float s2 = v.x*v.x + v.y*v.y + v.z*v.z + v.w*v.w;
  #pragma unroll
  for (int m = 1; m < 64; m <<= 1) {
    s  += __shfl_xor(s,  m, 64);
    s2 += __shfl_xor(s2, m, 64);
  }
  const float mean = s * (1.0f / CDIM);
  const float rstd = rsqrtf(s2 * (1.0f / CDIM) - mean * mean + 1e-3f);
  const float4 gv = ((const float4*)gam)[lane];
  const float4 bv = ((const float4*)bet)[lane];
  float4 o;
  o.x = (v.x - mean) * rstd * gv.x + bv.x;
  o.y = (v.y - mean) * rstd * gv.y + bv.y;
  o.z = (v.z - mean) * rstd * gv.z + bv.z;
  o.w = (v.w - mean) * rstd * gv.w + bv.w;
  ((float4*)(xnf + tok * CDIM))[lane] = o;
  half4v h;
  h[0] = (_Float16)o.x; h[1] = (_Float16)o.y;
  h[2] = (_Float16)o.z; h[3] = (_Float16)o.w;
  ((half4v*)(xnh + tok * CDIM))[lane] = h;
}

// ---------------- projection GEMM: out[tok][j] = in[tok][:] @ w[:, jstrip] + b
// modes: 0=Q (fold scale*log2e), 1=K, 2=V (transposed [b][c][n] output), 3=P (fp32 + residual)
__global__ __launch_bounds__(256, 2) void proj_kernel(
    const _Float16* __restrict__ inh,
    const float* __restrict__ wq_, const float* __restrict__ bq_,
    const float* __restrict__ wk_, const float* __restrict__ bk_,
    const float* __restrict__ wv_, const float* __restrict__ bv_,
    const float* __restrict__ wp_, const float* __restrict__ bp_,
    _Float16* __restrict__ qg, _Float16* __restrict__ kg, _Float16* __restrict__ vtg,
    const float* __restrict__ xnf, float* __restrict__ outf,
    int mode_base) {
  extern __shared__ char smem[];
  const int mode = mode_base + blockIdx.z;
  const float* wsel = (mode == 0) ? wq_ : (mode == 1) ? wk_ : (mode == 2) ? wv_ : wp_;
  const float* bsel = (mode == 0) ? bq_ : (mode == 1) ? bk_ : (mode == 2) ? bv_ : bp_;

  const int tid = threadIdx.x;
  const int lane = tid & 63;
  const int wid  = tid >> 6;     // 0..3
  const int g    = lane >> 4;    // 0..3
  const int lr   = lane & 15;
  const int jstrip = blockIdx.y; // 0..3
  const size_t tok0 = (size_t)blockIdx.x * 512;

  char* wt   = smem;             // [64 j][256 c] f16, XOR-swizzled (32KB)
  char* tile = smem + 32768;     // [64 tok][256 c] f16, swizzled (32KB); reused as out staging

  // stage w^T (fp32 -> f16, transpose, swizzle): once per block
  for (int i = 0; i < 64; ++i) {
    int idx = i * 256 + tid;
    int c = idx >> 6, j = idx & 63;
    float val = wsel[(size_t)c * CDIM + jstrip * 64 + j];
    *(_Float16*)(wt + j * 512 + ((((c >> 3) ^ (j & 7))) << 4) + ((c & 7) << 1)) =
        (_Float16)val;
  }
  float bjv[4];
  #pragma unroll
  for (int jc = 0; jc < 4; ++jc) bjv[jc] = bsel[jstrip * 64 + jc * 16 + lr];
  __syncthreads();

  for (int t = 0; t < 8; ++t) {
    const size_t trow0 = tok0 + t * 64;
    // stage input tile [64][256] f16; linear LDS dest + inverse-swizzled global source
    #pragma unroll
    for (int i = 0; i < 8; ++i) {
      int pbase = (i * 4 + wid) * 64;
      int p = pbase + lane;
      int row = p >> 5, sl = p & 31;
      gload_lds16(inh + (trow0 + row) * CDIM + (size_t)((sl ^ (row & 7)) * 8),
                  tile + pbase * 16);
    }
    __syncthreads();

    f32x4 acc[4] = {{0,0,0,0},{0,0,0,0},{0,0,0,0},{0,0,0,0}};
    #pragma unroll
    for (int kc = 0; kc < 8; ++kc) {
      half8 a = *(const half8*)(tile + (wid * 16 + lr) * 512 +
                                ((((kc << 2) | g) ^ (lr & 7)) << 4));
      #pragma unroll
      for (int jc = 0; jc < 4; ++jc) {
        half8 bf = *(const half8*)(wt + (jc * 16 + lr) * 512 +
                                   ((((kc << 2) | g) ^ (lr & 7)) << 4));
        acc[jc] = __builtin_amdgcn_mfma_f32_16x16x32_f16(a, bf, acc[jc], 0, 0, 0);
      }
    }

    if (mode == 3) {
      // fp32 out + bias + residual(xn), direct coalesced stores (64B/16 lanes)
      #pragma unroll
      for (int jc = 0; jc < 4; ++jc) {
        #pragma unroll
        for (int r = 0; r < 4; ++r) {
          size_t row = trow0 + wid * 16 + g * 4 + r;
          size_t off = row * CDIM + jstrip * 64 + jc * 16 + lr;
          outf[off] = acc[jc][r] + bjv[jc] + xnf[off];
        }
      }
    } else {
      const float csc = (mode == 0) ? 0.09016844005556021f : 1.0f; // log2(e)/16
      __syncthreads();  // all LDS reads of tile done before reuse
      _Float16* ot = (_Float16*)tile;  // [64][72]
      #pragma unroll
      for (int jc = 0; jc < 4; ++jc)
        #pragma unroll
        for (int r = 0; r < 4; ++r)
          ot[(wid * 16 + g * 4 + r) * 72 + jc * 16 + lr] =
              (_Float16)((acc[jc][r] + bjv[jc]) * csc);
      __syncthreads();
      if (mode != 2) {
        _Float16* dst = (mode == 0) ? qg : kg;
        #pragma unroll
        for (int it = 0; it < 2; ++it) {
          int s = it * 256 + tid;          // 512 slots: [64 rows][8 x 16B]
          int row = s >> 3, sl = s & 7;
          half8 vv = *(const half8*)(ot + row * 72 + sl * 8);
          *(half8*)(dst + (trow0 + row) * CDIM + jstrip * 64 + sl * 8) = vv;
        }
      } else {
        // transposed store: vt[b][c][n]
        #pragma unroll
        for (int it = 0; it < 2; ++it) {
          int s = it * 256 + tid;          // [64 j][8 n-slots]
          int j = s >> 3, ns = s & 7;
          half8 vv;
          #pragma unroll
          for (int e = 0; e < 8; ++e) vv[e] = ot[(ns * 8 + e) * 72 + j];
          size_t bb  = trow0 >> 12;        // batch
          size_t nin = (trow0 & 4095) + ns * 8;
          *(half8*)(vtg + ((size_t)bb * CDIM + jstrip * 64 + j) * NSEQ + nin) = vv;
        }
      }
    }
    __syncthreads();
  }
}

// ---------------- flash attention: QBLK=128, KVBLK=64, 8 waves
#define ATTN_LDS (32768 + 32768 + 16384 + 512)

__global__ __launch_bounds__(512, 2) void attn_kernel(
    const _Float16* __restrict__ qg, const _Float16* __restrict__ kg,
    const _Float16* __restrict__ vtg, _Float16* __restrict__ og) {
  extern __shared__ char smem[];
  char*  kbuf = smem;            // [64 kv][256 c] f16, swizzled (32KB)
  char*  vbuf = smem + 32768;    // [256 d][64 kv] f16, swizzled (32KB)
  char*  pbuf = smem + 65536;    // [128 q][64 kv] f16, swizzled (16KB)
  float* alf  = (float*)(smem + 81920);  // [128] alpha / 1/l

  const int tid  = threadIdx.x;
  const int lane = tid & 63;
  const int wid  = tid >> 6;     // 0..7
  const int g    = lane >> 4;
  const int lr   = lane & 15;
  const int b    = blockIdx.x & 7;      // XCD-affine: batch pinned to one XCD's L2
  const int n0   = (blockIdx.x >> 3) * 128;
  const int qhalf = wid & 1;     // PV: q-half
  const int dquad = wid >> 1;    // PV: d-quarter

  // Q fragments (this wave's 16 S-rows), scale already folded in
  half8 qf[8];
  const _Float16* qp = qg + ((size_t)(b * NSEQ + n0 + wid * 16 + lr)) * CDIM + g * 8;
  #pragma unroll
  for (int kc = 0; kc < 8; ++kc) qf[kc] = *(const half8*)(qp + kc * 32);

  f32x4 o[4][4];  // [mi][dc] : O[qhalf*64 + mi*16 + 4g+r][dquad*64 + dc*16 + lr]
  #pragma unroll
  for (int mi = 0; mi < 4; ++mi)
    #pragma unroll
    for (int dc = 0; dc < 4; ++dc) o[mi][dc] = (f32x4){0,0,0,0};
  f32x4 mrow = {-1e30f, -1e30f, -1e30f, -1e30f};
  f32x4 lrow = {0, 0, 0, 0};

  for (int t = 0; t < 64; ++t) {
    const int kv0 = t * 64;
    __syncthreads();  // prev iter's K/V reads done
    // stage K [64][256] and V^T [256][64] (linear LDS + inverse-swizzled source)
    #pragma unroll
    for (int i = 0; i < 4; ++i) {
      int pbase = (i * 8 + wid) * 64;
      int p = pbase + lane;
      int row = p >> 5, sl = p & 31;
      gload_lds16(kg + ((size_t)(b * NSEQ + kv0 + row)) * CDIM + (sl ^ (row & 7)) * 8,
                  kbuf + pbase * 16);
    }
    #pragma unroll
    for (int i = 0; i < 4; ++i) {
      int pbase = (i * 8 + wid) * 64;
      int p = pbase + lane;
      int d = p >> 3, sl = p & 7;
      gload_lds16(vtg + ((size_t)(b * CDIM + d)) * NSEQ + kv0 + (sl ^ (d & 7)) * 8,
                  vbuf + pbase * 16);
    }
    __syncthreads();  // staging visible

    // ---- S = Q K^T (this wave's 16 q rows x 64 kv)
    f32x4 sacc[4] = {{0,0,0,0},{0,0,0,0},{0,0,0,0},{0,0,0,0}};
    #pragma unroll
    for (int kc = 0; kc < 8; ++kc) {
      #pragma unroll
      for (int nc = 0; nc < 4; ++nc) {
        half8 kf = *(const half8*)(kbuf + (nc * 16 + lr) * 512 +
                                   ((((kc << 2) | g) ^ (lr & 7)) << 4));
        sacc[nc] = __builtin_amdgcn_mfma_f32_16x16x32_f16(qf[kc], kf, sacc[nc], 0, 0, 0);
      }
    }

    // ---- online softmax (rows live in 16-lane groups; reduce via shfl_xor 1..8)
    f32x4 pm = vmax4(vmax4(sacc[0], sacc[1]), vmax4(sacc[2], sacc[3]));
    #pragma unroll
    for (int m = 1; m < 16; m <<= 1) {
      f32x4 tv;
      tv[0] = __shfl_xor(pm[0], m, 64); tv[1] = __shfl_xor(pm[1], m, 64);
      tv[2] = __shfl_xor(pm[2], m, 64); tv[3] = __shfl_xor(pm[3], m, 64);
      pm = vmax4(pm, tv);
    }
    f32x4 mnew = vmax4(mrow, pm);
    f32x4 al;
    #pragma unroll
    for (int r = 0; r < 4; ++r) al[r] = exp2f(mrow[r] - mnew[r]);

    f32x4 rs = {0, 0, 0, 0};
    #pragma unroll
    for (int nc = 0; nc < 4; ++nc) {
      f32x4 p;
      #pragma unroll
      for (int r = 0; r < 4; ++r) p[r] = exp2f(sacc[nc][r] - mnew[r]);
      rs += p;
      int slot = nc * 2 + (lr >> 3);
      #pragma unroll
      for (int r = 0; r < 4; ++r) {
        int row = wid * 16 + g * 4 + r;
        *(_Float16*)(pbuf + row * 128 + ((slot ^ ((g * 4 + r) & 7)) << 4) +
                     ((lr & 7) << 1)) = (_Float16)p[r];
      }
    }
    #pragma unroll
    for (int m = 1; m < 16; m <<= 1) {
      f32x4 tv;
      tv[0] = __shfl_xor(rs[0], m, 64); tv[1] = __shfl_xor(rs[1], m, 64);
      tv[2] = __shfl_xor(rs[2], m, 64); tv[3] = __shfl_xor(rs[3], m, 64);
      rs += tv;
    }
    lrow = lrow * al + rs;
    mrow = mnew;
    #pragma unroll
    for (int r = 0; r < 4; ++r) alf[wid * 16 + g * 4 + r] = al[r];
    __syncthreads();  // P + alpha visible

    // ---- PV: wave handles q-half x d-quarter; rescale O then accumulate
    #pragma unroll
    for (int mi = 0; mi < 4; ++mi) {
      f32x4 av = *(const f32x4*)(alf + qhalf * 64 + mi * 16 + g * 4);
      #pragma unroll
      for (int dc = 0; dc < 4; ++dc) o[mi][dc] *= av;
    }
    #pragma unroll
    for (int kc2 = 0; kc2 < 2; ++kc2) {
      half8 pf[4];
      #pragma unroll
      for (int mi = 0; mi < 4; ++mi)
        pf[mi] = *(const half8*)(pbuf + (qhalf * 64 + mi * 16 + lr) * 128 +
                                 ((((kc2 << 2) | g) ^ (lr & 7)) << 4));
      #pragma unroll
      for (int dc = 0; dc < 4; ++dc) {
        int d = dquad * 64 + dc * 16 + lr;
        half8 vf = *(const half8*)(vbuf + d * 128 +
                                   ((((kc2 << 2) | g) ^ (lr & 7)) << 4));
        #pragma unroll
        for (int mi = 0; mi < 4; ++mi)
          o[mi][dc] = __builtin_amdgcn_mfma_f32_16x16x32_f16(pf[mi], vf, o[mi][dc], 0, 0, 0);
      }
    }
  }

  // ---- finalize: publish 1/l, normalize, stage O in LDS, coalesced store
  __syncthreads();
  #pragma unroll
  for (int r = 0; r < 4; ++r) alf[wid * 16 + g * 4 + r] = 1.0f / lrow[r];
  __syncthreads();
  _Float16* oL = (_Float16*)smem;  // [128][256]
  #pragma unroll
  for (int mi = 0; mi < 4; ++mi) {
    f32x4 lv = *(const f32x4*)(alf + qhalf * 64 + mi * 16 + g * 4);
    #pragma unroll
    for (int dc = 0; dc < 4; ++dc) {
      #pragma unroll
      for (int r = 0; r < 4; ++r)
        oL[(qhalf * 64 + mi * 16 + g * 4 + r) * 256 + dquad * 64 + dc * 16 + lr] =
            (_Float16)(o[mi][dc][r] * lv[r]);
    }
  }
  __syncthreads();
  #pragma unroll
  for (int i = 0; i < 8; ++i) {
    int p = i * 512 + tid;
    int row = p >> 5, sl = p & 31;
    *(half8*)(og + ((size_t)(b * NSEQ + n0 + row)) * CDIM + sl * 8) =
        *(const half8*)(oL + row * 256 + sl * 8);
  }
}

// ---------------- launcher
extern "C" void kernel_launch(void* const* d_in, const int* in_sizes, int n_in,
                              void* d_out, int out_size, void* d_ws, size_t ws_size,
                              hipStream_t stream) {
  const float* x   = (const float*)d_in[0];
  const float* gam = (const float*)d_in[1];
  const float* bet = (const float*)d_in[2];
  const float* wq  = (const float*)d_in[3];
  const float* bq  = (const float*)d_in[4];
  const float* wk  = (const float*)d_in[5];
  const float* bk  = (const float*)d_in[6];
  const float* wv  = (const float*)d_in[7];
  const float* bv  = (const float*)d_in[8];
  const float* wp  = (const float*)d_in[9];
  const float* bp  = (const float*)d_in[10];
  float* out = (float*)d_out;

  char* ws = (char*)d_ws;
  float*    xnf = (float*)ws;                             // 32MB fp32 xn (residual)
  _Float16* xnh = (_Float16*)(ws + (32u << 20));          // 16MB f16 xn
  _Float16* qh  = (_Float16*)(ws + (48u << 20));          // 16MB q (scaled)
  _Float16* kh  = (_Float16*)(ws + (64u << 20));          // 16MB k
  _Float16* vth = (_Float16*)(ws + (80u << 20));          // 16MB v^T [b][c][n]
  _Float16* oh  = (_Float16*)(ws + (96u << 20));          // 16MB attn out

  (void)hipFuncSetAttribute((const void*)proj_kernel,
                            hipFuncAttributeMaxDynamicSharedMemorySize, 65536);
  (void)hipFuncSetAttribute((const void*)attn_kernel,
                            hipFuncAttributeMaxDynamicSharedMemorySize, ATTN_LDS);

  ln_kernel<<<NTOK / 4, 256, 0, stream>>>(x, gam, bet, xnf, xnh);
  proj_kernel<<<dim3(64, 4, 3), 256, 65536, stream>>>(
      xnh, wq, bq, wk, bk, wv, bv, wp, bp, qh, kh, vth, xnf, out, 0);
  attn_kernel<<<256, 512, ATTN_LDS, stream>>>(qh, kh, vth, oh);
  proj_kernel<<<dim3(64, 4, 1), 256, 65536, stream>>>(
      oh, wq, bq, wk, bk, wv, bv, wp, bp, qh, kh, vth, xnf, out, 3);
}